// Round 5
// baseline (7587.417 us; speedup 1.0000x reference)
//
#include <hip/hip_runtime.h>

// ---------------------------------------------------------------------------
// BasicModel_43387759624704: 2-layer GRU (T=512, B=256, H=512, COV=128) with
// ragged-length masking, covariate projection head, and exp(-dist) head.
// ROUND 5: inputs/outputs are FLOAT32 (per the reference dtypes). MFMA
// operands are converted to bf16 in workspace; accumulation/state/output f32.
// Structure kept from round 4: one GRU timestep per launch, stream-ordered,
// no inter-block sync (correctness bisect: only the dtype changed).
// ---------------------------------------------------------------------------

typedef unsigned short u16;
typedef __attribute__((ext_vector_type(8))) short short8;
typedef short8 bf16x8;
typedef __attribute__((ext_vector_type(4))) float f32x4;

#define T_DIM 512
#define B_DIM 256
#define H_DIM 512
#define G3H   1536
#define BT    131072        // 256*512
#define XPK   192           // padded K for layer-0 input GEMM (129 -> 192)
#define PRED_ELEMS 16875264 // 256*511*129

__device__ __forceinline__ u16 f2bf(float f) {  // RNE
    union { float f; unsigned i; } v; v.f = f;
    unsigned i = v.i;
    return (u16)((i + 0x7FFFu + ((i >> 16) & 1u)) >> 16);
}
__device__ __forceinline__ float bf2f(u16 u) {
    union { unsigned i; float f; } v; v.i = ((unsigned)u) << 16; return v.f;
}
__device__ __forceinline__ float sigm(float x) { return 1.f / (1.f + __expf(-x)); }
__device__ __forceinline__ float tanh_f(float x) {
    float ax = fabsf(x);
    float e = __expf(-2.f * ax);
    float t = (1.f - e) / (1.f + e);
    return x < 0.f ? -t : t;
}

// ---------------------------------------------------------------------------
// f32 [rows][srcK] -> bf16 [rows][dstK] (zero-pad cols >= srcK)
__global__ void cvt_pad_kernel(const float* __restrict__ src, u16* __restrict__ dst,
                               int rows, int srcK, int dstK) {
    int n = rows * dstK;
    for (int idx = blockIdx.x * blockDim.x + threadIdx.x; idx < n;
         idx += gridDim.x * blockDim.x) {
        int row = idx / dstK, col = idx - row * dstK;
        float v = (col < srcK) ? src[(size_t)row * srcK + col] : 0.f;
        dst[idx] = f2bf(v);
    }
}

// W_cov f32 [128][513] -> bf16 [128][512] + f32 wlast[128] (col 512)
__global__ void cvt_wcov_kernel(const float* __restrict__ Wcov,
                                u16* __restrict__ WcovBf, float* __restrict__ wlastf) {
    int idx0 = blockIdx.x * blockDim.x + threadIdx.x;
    for (int idx = idx0; idx < 128 * 512; idx += gridDim.x * blockDim.x) {
        int row = idx >> 9, col = idx & 511;
        WcovBf[idx] = f2bf(Wcov[row * 513 + col]);
    }
    if (idx0 < 128) wlastf[idx0] = Wcov[idx0 * 513 + 512];
}

// ---------------------------------------------------------------------------
// C[m][n] = sum_k A[m][k]*B[n][k] + bias[n]; A,B bf16 K-major; bias f32; C bf16
__global__ __launch_bounds__(256) void gemm_bias_kernel(
    const u16* __restrict__ A, int lda, const u16* __restrict__ B, int ldb,
    const float* __restrict__ bias, u16* __restrict__ C, int ldc, int K) {
    __shared__ __attribute__((aligned(16))) u16 Ash[128 * 72];
    __shared__ __attribute__((aligned(16))) u16 Bsh[128 * 72];
    const int tid = threadIdx.x, lane = tid & 63, w = tid >> 6;
    const int m0 = blockIdx.y * 128, n0 = blockIdx.x * 128;
    const int r0 = (w & 1) * 64, c0 = (w >> 1) * 64;
    const int am = lane & 15, aq = lane >> 4;
    f32x4 acc[4][4] = {};
    for (int kt = 0; kt < K; kt += 64) {
        __syncthreads();
#pragma unroll
        for (int s = 0; s < 4; ++s) {
            int cid = tid + s * 256, row = cid >> 3, q = cid & 7;
            *(short8*)&Ash[row * 72 + q * 8] =
                *(const short8*)(A + (size_t)(m0 + row) * lda + kt + q * 8);
            *(short8*)&Bsh[row * 72 + q * 8] =
                *(const short8*)(B + (size_t)(n0 + row) * ldb + kt + q * 8);
        }
        __syncthreads();
#pragma unroll
        for (int ks = 0; ks < 2; ++ks) {
            const int kof = ks * 32 + aq * 8;
            bf16x8 a[4], bb[4];
#pragma unroll
            for (int f = 0; f < 4; ++f)
                a[f] = *(short8*)&Ash[(r0 + f * 16 + am) * 72 + kof];
#pragma unroll
            for (int f = 0; f < 4; ++f)
                bb[f] = *(short8*)&Bsh[(c0 + f * 16 + am) * 72 + kof];
#pragma unroll
            for (int fi = 0; fi < 4; ++fi)
#pragma unroll
                for (int fj = 0; fj < 4; ++fj)
                    acc[fi][fj] = __builtin_amdgcn_mfma_f32_16x16x32_bf16(
                        a[fi], bb[fj], acc[fi][fj], 0, 0, 0);
        }
    }
#pragma unroll
    for (int fj = 0; fj < 4; ++fj) {
        const int col = n0 + c0 + fj * 16 + am;
        const float bia = bias[col];
#pragma unroll
        for (int fi = 0; fi < 4; ++fi) {
#pragma unroll
            for (int r = 0; r < 4; ++r) {
                const int row = m0 + r0 + fi * 16 + aq * 4 + r;
                C[(size_t)row * ldc + col] = f2bf(acc[fi][fj][r] + bia);
            }
        }
    }
}

// ---------------------------------------------------------------------------
// ONE GRU timestep. Grid (32 col-blocks, 16 row-groups) = 512 blocks.
// gh = h_{t-1} @ Whh^T for a 16-batch x 16-col patch (3 gates); Whh read from
// global bf16 (L2-hot); h from bf16 parity buffer (or h0bf at t=0); f32 carry.
__global__ __launch_bounds__(256) void scan_step_kernel(
    const u16* __restrict__ gi_t,    // [256][1536] this step's input gates (bf16)
    const u16* __restrict__ Whh,     // [1536][512] bf16
    const float* __restrict__ bhh,   // [1536] f32
    const int* __restrict__ lengths, // [256]
    const float* __restrict__ h0l,   // [256][512] f32 (layer slice)
    const u16* __restrict__ h0bfl,   // [256][512] bf16 (layer slice)
    u16* __restrict__ o_t,           // [256][512] bf16 out
    u16* __restrict__ hbf,           // [2][256][512] bf16 state (parity)
    float* __restrict__ hc,          // [2][256][512] f32 carry (parity)
    int t) {
    __shared__ __attribute__((aligned(16))) float P[4 * 3 * 256];
    const int tid = threadIdx.x, lane = tid & 63, w = tid >> 6;
    const int n0 = blockIdx.x * 16, b0 = blockIdx.y * 16;
    const int am = lane & 15, aq = lane >> 4;
    const u16* Asrc = (t == 0) ? h0bfl : (hbf + (size_t)((t - 1) & 1) * BT);
    f32x4 ar = {}, az = {}, an = {};
#pragma unroll
    for (int kb = 0; kb < 4; ++kb) {
        const int k = w * 128 + kb * 32 + aq * 8;
        bf16x8 a  = *(const short8*)(Asrc + (size_t)(b0 + am) * 512 + k);
        bf16x8 wr = *(const short8*)(Whh + (size_t)(n0 + am) * 512 + k);
        bf16x8 wz = *(const short8*)(Whh + (size_t)(512 + n0 + am) * 512 + k);
        bf16x8 wn = *(const short8*)(Whh + (size_t)(1024 + n0 + am) * 512 + k);
        ar = __builtin_amdgcn_mfma_f32_16x16x32_bf16(a, wr, ar, 0, 0, 0);
        az = __builtin_amdgcn_mfma_f32_16x16x32_bf16(a, wz, az, 0, 0, 0);
        an = __builtin_amdgcn_mfma_f32_16x16x32_bf16(a, wn, an, 0, 0, 0);
    }
#pragma unroll
    for (int r = 0; r < 4; ++r) {
        P[(w * 3 + 0) * 256 + (aq * 4 + r) * 16 + am] = ar[r];
        P[(w * 3 + 1) * 256 + (aq * 4 + r) * 16 + am] = az[r];
        P[(w * 3 + 2) * 256 + (aq * 4 + r) * 16 + am] = an[r];
    }
    __syncthreads();
    const int m = tid >> 4, c = tid & 15;
    const int b = b0 + m, col = n0 + c;
    float Cr = bhh[col];
    float Cz = bhh[512 + col];
    float Cn = bhh[1024 + col];
#pragma unroll
    for (int w2 = 0; w2 < 4; ++w2) {
        Cr += P[(w2 * 3 + 0) * 256 + tid];
        Cz += P[(w2 * 3 + 1) * 256 + tid];
        Cn += P[(w2 * 3 + 2) * 256 + tid];
    }
    const float hprev = (t == 0) ? h0l[(size_t)b * 512 + col]
                                 : hc[(size_t)((t - 1) & 1) * BT + (size_t)b * 512 + col];
    const size_t gib = (size_t)b * G3H + col;
    const float r_ = sigm(bf2f(gi_t[gib]) + Cr);
    const float z_ = sigm(bf2f(gi_t[gib + 512]) + Cz);
    const float n_ = tanh_f(bf2f(gi_t[gib + 1024]) + r_ * Cn);
    const float hnew = (1.f - z_) * n_ + z_ * hprev;
    const bool valid = t < lengths[b];
    const float h = valid ? hnew : hprev;
    o_t[(size_t)b * 512 + col] = f2bf(valid ? hnew : 0.f);
    hbf[(size_t)(t & 1) * BT + (size_t)b * 512 + col] = f2bf(h);
    hc [(size_t)(t & 1) * BT + (size_t)b * 512 + col] = h;
}

// ---------------------------------------------------------------------------
// preds[b][t][c] = mask * (o1[t,b,:]@WcovBf[c,:] + x[t,b,0]*wlast[c] + bcov[c])
// f32 output. grid (ceil(TC/64), 256).
__global__ __launch_bounds__(256) void preds_kernel(
    const u16* __restrict__ o1c, const u16* __restrict__ WcovBf,
    const float* __restrict__ wlastf, const float* __restrict__ bcov,
    const float* __restrict__ x, const int* __restrict__ lengths,
    float* __restrict__ out, int t0, int TC) {
    __shared__ __attribute__((aligned(16))) u16 Ash[64 * 72];
    __shared__ __attribute__((aligned(16))) u16 Bsh[128 * 72];
    const int tid = threadIdx.x, lane = tid & 63, w = tid >> 6;
    const int tb0 = blockIdx.x * 64, b = blockIdx.y;
    const int am = lane & 15, aq = lane >> 4;
    f32x4 acc[8] = {};
    for (int kt = 0; kt < 512; kt += 64) {
        __syncthreads();
#pragma unroll
        for (int s = 0; s < 2; ++s) {
            int cid = tid + s * 256, row = cid >> 3, q = cid & 7;
            int tl = tb0 + row;
            short8 v = {};
            if (tl < TC && (t0 + tl) < 511)
                v = *(const short8*)(o1c + ((size_t)tl * 256 + b) * 512 + kt + q * 8);
            *(short8*)&Ash[row * 72 + q * 8] = v;
        }
#pragma unroll
        for (int s = 0; s < 4; ++s) {
            int cid = tid + s * 256, row = cid >> 3, q = cid & 7;
            *(short8*)&Bsh[row * 72 + q * 8] =
                *(const short8*)(WcovBf + (size_t)row * 512 + kt + q * 8);
        }
        __syncthreads();
#pragma unroll
        for (int ks = 0; ks < 2; ++ks) {
            const int kof = ks * 32 + aq * 8;
            bf16x8 a = *(short8*)&Ash[(w * 16 + am) * 72 + kof];
#pragma unroll
            for (int fj = 0; fj < 8; ++fj) {
                bf16x8 bb = *(short8*)&Bsh[(fj * 16 + am) * 72 + kof];
                acc[fj] = __builtin_amdgcn_mfma_f32_16x16x32_bf16(a, bb, acc[fj], 0, 0, 0);
            }
        }
    }
    const int len = lengths[b];
#pragma unroll
    for (int r = 0; r < 4; ++r) {
        const int tl = tb0 + w * 16 + aq * 4 + r;
        const int t = t0 + tl;
        if (tl >= TC || t >= 511) continue;
        const float tim = x[(size_t)t * (256 * 129) + b * 129];
        const bool valid = t < (len - 1);
        const size_t ob = (size_t)b * (511 * 129) + (size_t)t * 129;
#pragma unroll
        for (int fj = 0; fj < 8; ++fj) {
            const int cc = fj * 16 + am;
            float v = acc[fj][r] + bcov[cc] + tim * wlastf[cc];
            out[ob + cc] = valid ? v : 0.f;
        }
    }
    if (tid < 64) {  // channel 128 is always zero
        int tl = tb0 + tid, t = t0 + tl;
        if (tl < TC && t < 511)
            out[(size_t)b * (511 * 129) + (size_t)t * 129 + 128] = 0.f;
    }
}

// ---------------------------------------------------------------------------
// dist[i][p] = exp(-(last_flat[i] @ W_par[p] + b_par[p])), f32 out.
// last_flat row i: layer l=i>>7, batches bb=(2i)&255 and bb+1 (512 each).
__global__ void dist_kernel(const float* __restrict__ hl0,
                            const float* __restrict__ hl1,
                            const float* __restrict__ Wpar,
                            const float* __restrict__ bpar, float* __restrict__ out) {
    const int w = threadIdx.x >> 6, lane = threadIdx.x & 63;
    const float bp0 = bpar[0], bp1 = bpar[1];
    for (int rr = 0; rr < 8; ++rr) {
        const int i = (blockIdx.x * 4 + w) * 8 + rr;
        const int l = i >> 7, bb = (2 * i) & 255;
        const float* base = (l ? hl1 : hl0) + (size_t)bb * 512;
        float a0 = 0.f, a1 = 0.f;
#pragma unroll
        for (int cc = 0; cc < 16; ++cc) {
            const int k = cc * 64 + lane;
            const float v = base[k];
            a0 += v * Wpar[k];
            a1 += v * Wpar[1024 + k];
        }
#pragma unroll
        for (int off = 32; off; off >>= 1) {
            a0 += __shfl_down(a0, off);
            a1 += __shfl_down(a1, off);
        }
        if (lane == 0) {
            out[PRED_ELEMS + i * 2 + 0] = __expf(-(a0 + bp0));
            out[PRED_ELEMS + i * 2 + 1] = __expf(-(a1 + bp1));
        }
    }
}

// ---------------------------------------------------------------------------
extern "C" void kernel_launch(void* const* d_in, const int* in_sizes, int n_in,
                              void* d_out, int out_size, void* d_ws, size_t ws_size,
                              hipStream_t stream) {
    const float* x    = (const float*)d_in[0];
    const int* lens   = (const int*)d_in[1];
    const float* h0   = (const float*)d_in[2];
    const float* Wih0 = (const float*)d_in[3];
    const float* Whh0 = (const float*)d_in[4];
    const float* bih0 = (const float*)d_in[5];
    const float* bhh0 = (const float*)d_in[6];
    const float* Wih1 = (const float*)d_in[7];
    const float* Whh1 = (const float*)d_in[8];
    const float* bih1 = (const float*)d_in[9];
    const float* bhh1 = (const float*)d_in[10];
    const float* Wcov = (const float*)d_in[11];
    const float* bcov = (const float*)d_in[12];
    const float* Wpar = (const float*)d_in[13];
    const float* bpar = (const float*)d_in[14];
    float* out = (float*)d_out;
    char* wsb = (char*)d_ws;

    size_t off = 0;
    auto take = [&](size_t bytes) -> size_t {
        size_t r = off; off += (bytes + 255) & ~(size_t)255; return r;
    };
    // fixed buffers
    const size_t oHc0   = take((size_t)2 * BT * 4);     // layer0 f32 carry (parity)
    const size_t oHc1   = take((size_t)2 * BT * 4);     // layer1 f32 carry (parity)
    const size_t oHbf0  = take((size_t)2 * BT * 2);     // layer0 bf16 state (parity)
    const size_t oHbf1  = take((size_t)2 * BT * 2);     // layer1 bf16 state (parity)
    const size_t oH0bf  = take((size_t)2 * BT * 2);     // bf16(h0) both layers
    const size_t oWih0b = take((size_t)G3H * XPK * 2);  // bf16 Wih0 padded
    const size_t oWih1b = take((size_t)G3H * 512 * 2);  // bf16 Wih1
    const size_t oWhh0b = take((size_t)G3H * 512 * 2);  // bf16 Whh0
    const size_t oWhh1b = take((size_t)G3H * 512 * 2);  // bf16 Whh1
    const size_t oWcovb = take((size_t)128 * 512 * 2);  // bf16 Wcov aligned
    const size_t oWlast = take(512);                    // f32 wlast[128]
    const size_t fixed = off;

    // chunk size: largest TC whose per-chunk buffers fit remaining workspace
    const size_t per = (size_t)256 * XPK * 2 + (size_t)256 * G3H * 2 +
                       2 * (size_t)256 * 512 * 2 + 2048;
    const size_t remain = ws_size > fixed ? ws_size - fixed : 0;
    int TC = 1;
    const int cands[10] = {512, 256, 128, 64, 32, 16, 8, 4, 2, 1};
    for (int i = 0; i < 10; ++i)
        if ((size_t)cands[i] * per <= remain) { TC = cands[i]; break; }

    const size_t oXbf = take((size_t)TC * 256 * XPK * 2);
    const size_t oGi  = take((size_t)TC * 256 * G3H * 2);
    const size_t oO0  = take((size_t)TC * 256 * 512 * 2);
    const size_t oO1  = take((size_t)TC * 256 * 512 * 2);

    float* hc0  = (float*)(wsb + oHc0);
    float* hc1  = (float*)(wsb + oHc1);
    u16* hbf0   = (u16*)(wsb + oHbf0);
    u16* hbf1   = (u16*)(wsb + oHbf1);
    u16* h0bf   = (u16*)(wsb + oH0bf);
    u16* wih0b  = (u16*)(wsb + oWih0b);
    u16* wih1b  = (u16*)(wsb + oWih1b);
    u16* whh0b  = (u16*)(wsb + oWhh0b);
    u16* whh1b  = (u16*)(wsb + oWhh1b);
    u16* wcovb  = (u16*)(wsb + oWcovb);
    float* wlastf = (float*)(wsb + oWlast);
    u16* xbfc   = (u16*)(wsb + oXbf);
    u16* gic    = (u16*)(wsb + oGi);
    u16* o0c    = (u16*)(wsb + oO0);
    u16* o1c    = (u16*)(wsb + oO1);

    // one-time weight conversions (f32 -> bf16)
    cvt_pad_kernel<<<288, 256, 0, stream>>>(Wih0, wih0b, G3H, 129, XPK);
    cvt_pad_kernel<<<768, 256, 0, stream>>>(Wih1, wih1b, G3H, 512, 512);
    cvt_pad_kernel<<<768, 256, 0, stream>>>(Whh0, whh0b, G3H, 512, 512);
    cvt_pad_kernel<<<768, 256, 0, stream>>>(Whh1, whh1b, G3H, 512, 512);
    cvt_pad_kernel<<<256, 256, 0, stream>>>(h0, h0bf, 512, 512, 512);
    cvt_wcov_kernel<<<64, 256, 0, stream>>>(Wcov, wcovb, wlastf);

    for (int t0 = 0; t0 < T_DIM; t0 += TC) {
        // convert+pad this chunk of x: [TC*256][129] f32 -> [TC*256][192] bf16
        int n = TC * 256 * XPK;
        int pg = (n + 255) / 256; if (pg > 2048) pg = 2048;
        cvt_pad_kernel<<<pg, 256, 0, stream>>>(
            x + (size_t)t0 * 256 * 129, xbfc, TC * 256, 129, XPK);
        // gi0 = x @ Wih0^T + bih0
        gemm_bias_kernel<<<dim3(12, TC * 2), 256, 0, stream>>>(
            xbfc, XPK, wih0b, XPK, bih0, gic, G3H, XPK);
        for (int ts = 0; ts < TC; ++ts)
            scan_step_kernel<<<dim3(32, 16), 256, 0, stream>>>(
                gic + (size_t)ts * 256 * G3H, whh0b, bhh0, lens,
                h0, h0bf, o0c + (size_t)ts * 256 * 512, hbf0, hc0, t0 + ts);
        // gi1 = o0 @ Wih1^T + bih1
        gemm_bias_kernel<<<dim3(12, TC * 2), 256, 0, stream>>>(
            o0c, H_DIM, wih1b, H_DIM, bih1, gic, G3H, H_DIM);
        for (int ts = 0; ts < TC; ++ts)
            scan_step_kernel<<<dim3(32, 16), 256, 0, stream>>>(
                gic + (size_t)ts * 256 * G3H, whh1b, bhh1, lens,
                h0 + (size_t)BT, h0bf + (size_t)BT,
                o1c + (size_t)ts * 256 * 512, hbf1, hc1, t0 + ts);
        preds_kernel<<<dim3((TC + 63) / 64, 256), 256, 0, stream>>>(
            o1c, wcovb, wlastf, bcov, x, lens, out, t0, TC);
    }
    // final h lives at parity (T-1)&1 = 1
    dist_kernel<<<8, 256, 0, stream>>>(hc0 + BT, hc1 + BT, Wpar, bpar, out);
}